// Round 14
// baseline (603.970 us; speedup 1.0000x reference)
//
#include <hip/hip_runtime.h>

typedef short bf16x8 __attribute__((ext_vector_type(8)));
typedef float f32x4  __attribute__((ext_vector_type(4)));

#define N_USER 50000
#define N_ITEM 100000
#define N_NODES 150000
#define EMB 64
#define NNZ 2400000
#define BATCH 4096
#define NSAMP (3 * BATCH)     // 12288 sampled rows
#define NB 256                // row-range buckets
#define RPB 587               // rows per bucket (256*587 = 150272 >= 150001)
#define BS_GRID 256           // binning blocks
#define EPB (NNZ / BS_GRID)   // 9375 edges per block

// bf16 round-to-nearest-even; low 16 bits hold the bf16
__device__ __forceinline__ unsigned int bf16_rne(float x) {
    unsigned int u = __float_as_uint(x);
    return (u + 0x7fffu + ((u >> 16) & 1u)) >> 16;
}
__device__ __forceinline__ float bflo(unsigned int u) { return __uint_as_float(u << 16); }
__device__ __forceinline__ float bfhi(unsigned int u) { return __uint_as_float(u & 0xffff0000u); }

__device__ __forceinline__ void fma8(float v, const uint4& x, float* acc) {
    acc[0] = fmaf(v, bflo(x.x), acc[0]); acc[1] = fmaf(v, bfhi(x.x), acc[1]);
    acc[2] = fmaf(v, bflo(x.y), acc[2]); acc[3] = fmaf(v, bfhi(x.y), acc[3]);
    acc[4] = fmaf(v, bflo(x.z), acc[4]); acc[5] = fmaf(v, bfhi(x.z), acc[5]);
    acc[6] = fmaf(v, bflo(x.w), acc[6]); acc[7] = fmaf(v, bfhi(x.w), acc[7]);
}
__device__ __forceinline__ void mul8(const uint4& s, const float* a, float* o) {
    o[0] = bflo(s.x) * a[0]; o[1] = bfhi(s.x) * a[1];
    o[2] = bflo(s.y) * a[2]; o[3] = bfhi(s.y) * a[3];
    o[4] = bflo(s.z) * a[4]; o[5] = bfhi(s.z) * a[5];
    o[6] = bflo(s.w) * a[6]; o[7] = bfhi(s.w) * a[7];
}
__device__ __forceinline__ uint4 pack8(const float* f) {
    return make_uint4((bf16_rne(f[1]) << 16) | bf16_rne(f[0]),
                      (bf16_rne(f[3]) << 16) | bf16_rne(f[2]),
                      (bf16_rne(f[5]) << 16) | bf16_rne(f[4]),
                      (bf16_rne(f[7]) << 16) | bf16_rne(f[6]));
}

// ========= fused: bin_count (blocks 0..255) + ego cast / layer-0 slice / samp list =========
#define SEG_A (N_NODES * 16)          // 2,400,000 float4->uint2 ego init
#define SEG_B (NSAMP * EMB)           // 786,432 gather0
#define INIT_BLOCKS ((SEG_A + SEG_B + NSAMP) / 256)   // 12495
__global__ __launch_bounds__(256) void binit(const int* __restrict__ rows,
                                             int* __restrict__ cnt,
                                             const float4* __restrict__ ue4,
                                             const float4* __restrict__ ie4,
                                             const float* __restrict__ ue,
                                             const float* __restrict__ ie,
                                             const int* __restrict__ users,
                                             const int* __restrict__ pos,
                                             const int* __restrict__ neg,
                                             uint2* __restrict__ ego_bf,
                                             float* __restrict__ out,
                                             int* __restrict__ samp) {
    __shared__ int h[NB];
    const int t = threadIdx.x;
    if (blockIdx.x < BS_GRID) {                        // ---- bin_count part ----
        const int blk = blockIdx.x;
        h[t] = 0;
        __syncthreads();
        const int e0 = blk * EPB;
        for (int i = t; i < EPB; i += 256) atomicAdd(&h[rows[e0 + i] / RPB], 1);
        __syncthreads();
        cnt[t * BS_GRID + blk] = h[t];
        return;
    }
    int i = (blockIdx.x - BS_GRID) * 256 + t;
    if (i < SEG_A) {
        const int NU4 = N_USER * 16;
        float4 v = (i < NU4) ? ue4[i] : ie4[i - NU4];
        ego_bf[i] = make_uint2((bf16_rne(v.y) << 16) | bf16_rne(v.x),
                               (bf16_rne(v.w) << 16) | bf16_rne(v.z));
    } else if (i < SEG_A + SEG_B) {
        int tt = i - SEG_A;
        int r = tt >> 6, d = tt & 63;
        int seg = r >> 12, idx = r & (BATCH - 1);
        int node = (seg == 0) ? users[idx] : N_USER + ((seg == 1) ? pos[idx] : neg[idx]);
        float v = (node < N_USER) ? ue[(size_t)node * EMB + d]
                                  : ie[(size_t)(node - N_USER) * EMB + d];
        out[(size_t)r * 256 + d] = v;
    } else {
        int tt = i - SEG_A - SEG_B;   // < NSAMP
        int seg = tt >> 12, idx = tt & (BATCH - 1);
        samp[tt] = (seg == 0) ? users[idx] : N_USER + ((seg == 1) ? pos[idx] : neg[idx]);
    }
}

__global__ __launch_bounds__(1024) void scan64k(int* __restrict__ cnt) {
    __shared__ int s[1024];
    const int t = threadIdx.x;
    int loc[64], sum = 0;
#pragma unroll
    for (int i = 0; i < 64; ++i) { loc[i] = cnt[t * 64 + i]; sum += loc[i]; }
    s[t] = sum;
    for (int off = 1; off < 1024; off <<= 1) {
        __syncthreads();
        int add = (t >= off) ? s[t - off] : 0;
        __syncthreads();
        s[t] += add;
    }
    __syncthreads();
    int run = s[t] - sum;
#pragma unroll
    for (int i = 0; i < 64; ++i) { cnt[t * 64 + i] = run; run += loc[i]; }
}

__global__ __launch_bounds__(256) void bin_scatter(const int* __restrict__ rows,
                                                   const int* __restrict__ cols,
                                                   const float* __restrict__ vals,
                                                   const int* __restrict__ base,
                                                   int2* __restrict__ tmp_cv) {
    __shared__ int gbase[NB];
    __shared__ int cur[NB];
    const int t = threadIdx.x, blk = blockIdx.x;
    gbase[t] = base[t * BS_GRID + blk];
    cur[t] = 0;
    __syncthreads();
    const int e0 = blk * EPB;
    for (int i = t; i < EPB; i += 256) {
        int e = e0 + i;
        int r = rows[e];
        int b = r / RPB;
        int slot = atomicAdd(&cur[b], 1);
        unsigned vv = (__float_as_uint(vals[e]) & ~1023u) | (unsigned)(r - b * RPB);
        tmp_cv[gbase[b] + slot] = make_int2(cols[e], (int)vv);
    }
}

__global__ __launch_bounds__(256) void csr_from_bins(const int* __restrict__ base,
                                                     const int2* __restrict__ tmp_cv,
                                                     int2* __restrict__ ecv,
                                                     int* __restrict__ row_start,
                                                     int* __restrict__ dhist) {
    __shared__ int rcnt[RPB];
    __shared__ int excl[RPB + 1];
    __shared__ int sc[256];
    __shared__ int lhist[64];
    const int b = blockIdx.x;
    const int row0 = b * RPB;
    const int t = threadIdx.x;
    const int beg = base[b * BS_GRID];
    const int end = (b == NB - 1) ? NNZ : base[(b + 1) * BS_GRID];

    for (int i = t; i < RPB; i += 256) rcnt[i] = 0;
    if (t < 64) lhist[t] = 0;
    __syncthreads();
    for (int i = beg + t; i < end; i += 256) atomicAdd(&rcnt[tmp_cv[i].y & 1023], 1);
    __syncthreads();

    for (int i = t; i < RPB; i += 256)
        if (row0 + i < N_NODES) atomicAdd(&lhist[min(rcnt[i], 63)], 1);

    const int i0 = t * 3, i1 = i0 + 1, i2 = i0 + 2;
    int v0 = (i0 < RPB) ? rcnt[i0] : 0;
    int v1 = (i1 < RPB) ? rcnt[i1] : 0;
    int v2 = (i2 < RPB) ? rcnt[i2] : 0;
    int sum = v0 + v1 + v2;
    sc[t] = sum;
    for (int off = 1; off < 256; off <<= 1) {
        __syncthreads();
        int add = (t >= off) ? sc[t - off] : 0;
        __syncthreads();
        sc[t] += add;
    }
    __syncthreads();
    int ex = sc[t] - sum;
    if (i0 <= RPB) excl[i0] = ex;
    if (i1 <= RPB) excl[i1] = ex + v0;
    if (i2 <= RPB) excl[i2] = ex + v0 + v1;
    if (t < 64) atomicAdd(&dhist[t], lhist[t]);
    __syncthreads();

    int lim = N_NODES + 1 - row0;
    if (lim > RPB) lim = RPB;
    for (int i = t; i < lim; i += 256) row_start[row0 + i] = beg + excl[i];
    __syncthreads();
    for (int i = t; i < RPB; i += 256) rcnt[i] = excl[i];
    __syncthreads();
    for (int i = beg + t; i < end; i += 256) {
        int2 rec = tmp_cv[i];
        int r10 = rec.y & 1023;
        int dst = beg + atomicAdd(&rcnt[r10], 1);
        ecv[dst] = make_int2(rec.x, rec.y & ~1023);
    }
}

// ===== degree sort (descending = LPT): 64-bin bases, then rank-and-scatter =====
__global__ void deg_scan(const int* __restrict__ dhist, int* __restrict__ gcur) {
    __shared__ int h[64];
    int t = threadIdx.x;
    h[t] = dhist[t];
    __syncthreads();
    int b0 = 0;
    for (int b = 63; b > t; --b) b0 += h[b];
    gcur[t] = b0;
}

__global__ __launch_bounds__(256) void deg_scatter(const int* __restrict__ row_start,
                                                   int* __restrict__ gcur,
                                                   int* __restrict__ perm) {
    __shared__ int lcnt[64];
    __shared__ int goff[64];
    const int t = threadIdx.x;
    const int i = blockIdx.x * 256 + t;
    if (t < 64) lcnt[t] = 0;
    __syncthreads();
    int bin = 0, myrank = 0;
    const bool valid = i < N_NODES;
    if (valid) {
        bin = min(row_start[i + 1] - row_start[i], 63);
        myrank = atomicAdd(&lcnt[bin], 1);
    }
    __syncthreads();
    if (t < 64 && lcnt[t] > 0) goff[t] = atomicAdd(&gcur[t], lcnt[t]);
    __syncthreads();
    if (valid) perm[goff[bin] + myrank] = i;
}

// ======== kernel A: lean CSR gather in MFMA A-layout -> side_cs (no LDS, no AGPR) ========
// lane (m=lane&15, quad=lane>>4) owns dims {quad*8..+7, 32+quad*8..+7} of its row.
// 4-edge batched walk with prefetch; LPT perm via node_list. Epilogue: 4x16B stores.
__global__ __launch_bounds__(256, 6) void spmm_gather2(const int* __restrict__ row_start,
                                                       const int2* __restrict__ ecv,
                                                       const uint4* __restrict__ ego_bf,
                                                       uint4* __restrict__ side_cs, // n_rows x 16 uint4
                                                       const int* __restrict__ node_list,
                                                       int n_tiles) {
    const int t = threadIdx.x;
    const int wv = t >> 6, lane = t & 63;
    const int tile = blockIdx.x * 4 + wv;
    if (tile >= n_tiles) return;
    const int l15 = lane & 15, quad = lane >> 4;

    const int r = tile * 16 + l15;
    const int node = node_list[r];
    const int s0 = row_start[node];
    const int s1 = row_start[node + 1];

    float acc[16];
#pragma unroll
    for (int i = 0; i < 16; ++i) acc[i] = 0.f;

    int eCur = s0 + quad;
    int2 recCur = (eCur < s1) ? ecv[eCur] : make_int2(0, 0);
    for (int e0 = s0; e0 < s1; e0 += 4) {
        int en = e0 + 4 + quad;
        int2 recN = (en < s1) ? ecv[en] : make_int2(0, 0);
        int   c[4]; float v[4];
#pragma unroll
        for (int j = 0; j < 4; ++j) {
            c[j] = __shfl(recCur.x, l15 + j * 16);
            v[j] = __int_as_float(__shfl(recCur.y, l15 + j * 16));
        }
        uint4 x0[4], x1[4];
#pragma unroll
        for (int j = 0; j < 4; ++j) {
            x0[j] = ego_bf[(size_t)c[j] * 8 + quad];
            x1[j] = ego_bf[(size_t)c[j] * 8 + 4 + quad];
        }
#pragma unroll
        for (int j = 0; j < 4; ++j) {
            fma8(v[j], x0[j], acc);
            fma8(v[j], x1[j], acc + 8);
        }
        recCur = recN;
    }

    const uint4 sf0 = ego_bf[(size_t)node * 8 + quad];
    const uint4 sf1 = ego_bf[(size_t)node * 8 + 4 + quad];
    uint4* dst = side_cs + (size_t)r * 16;
    dst[quad]     = pack8(acc);                       // side K 0..31 (this quad's 8)
    dst[4 + quad] = pack8(acc + 8);                   // side K 32..63
    float cs[8];
    mul8(sf0, acc, cs);
    dst[8 + quad] = pack8(cs);                        // cs K 64..95
    mul8(sf1, acc + 8, cs);
    dst[12 + quad] = pack8(cs);                       // cs K 96..127
}

// ======== kernel B: MFMA GEMM [rows x 128]_bf16 @ [128 x 64] + bias/leaky/norm ========
// mode 0: perm-scatter ego_out (bf16) + inv_norm; mode 1: slot-direct x*inv -> out at col0.
// Piggy-backs the previous layer's output-slice gather on extra trailing blocks.
#define WROW 136
__global__ __launch_bounds__(256) void gemm_dense2(const uint4* __restrict__ side_cs,
                                                   const float* __restrict__ Wgc,
                                                   const float* __restrict__ bgc,
                                                   const float* __restrict__ Wbi,
                                                   const float* __restrict__ bbi,
                                                   ushort* __restrict__ ego_out,
                                                   float* __restrict__ inv_norm,
                                                   float* __restrict__ out,
                                                   const int* __restrict__ node_list,
                                                   int n_rows, int layer, int out_mode, int col0,
                                                   const ushort* __restrict__ g_ego,
                                                   const float* __restrict__ g_inv,
                                                   const int* __restrict__ g_samp,
                                                   int g_col0) {
    const int t = threadIdx.x;
    const int spmmBlocks = (n_rows + 255) >> 8;        // 16 tiles (256 rows) per block
    if ((int)blockIdx.x >= spmmBlocks) {
        int i = (blockIdx.x - spmmBlocks) * 256 + t;   // grid sized to exactly NSAMP*EMB
        int r = i >> 6, d = i & 63;
        int node = g_samp[r];
        float v = __uint_as_float(((unsigned int)g_ego[(size_t)node * 64 + d]) << 16) * g_inv[node];
        out[(size_t)r * 256 + g_col0 + d] = v;
        return;
    }

    __shared__ ushort wT[64 * WROW];                   // wT[n][k] = [Wgc|Wbi]^T, bf16
    const float* Wg = Wgc + layer * 4096;
    const float* Wb = Wbi + layer * 4096;
    for (int idx = t; idx < 8192; idx += 256) {
        int n = idx >> 7, k = idx & 127;
        float w = (k < 64) ? Wg[k * 64 + n] : Wb[(k - 64) * 64 + n];
        wT[n * WROW + k] = (ushort)bf16_rne(w);
    }
    __syncthreads();

    const int lane = t & 63;
    const int wv = t >> 6;
    const int l15 = lane & 15, quad = lane >> 4;

    const bf16x8* wt8 = (const bf16x8*)wT;             // row stride WROW/8 = 17
    bf16x8 bfr[4][4];
#pragma unroll
    for (int ks = 0; ks < 4; ++ks)
#pragma unroll
        for (int nt = 0; nt < 4; ++nt)
            bfr[ks][nt] = wt8[(nt * 16 + l15) * 17 + ks * 4 + quad];

    float bias[4];
#pragma unroll
    for (int nt = 0; nt < 4; ++nt) {
        int ccol = nt * 16 + l15;
        bias[nt] = bgc[layer * 64 + ccol] + bbi[layer * 64 + ccol];
    }

    const bf16x8* sc8 = (const bf16x8*)side_cs;        // row stride 16

    for (int i = 0; i < 4; ++i) {
        int tile = (blockIdx.x * 4 + wv) * 4 + i;
        int n0 = tile * 16;
        if (n0 >= n_rows) break;
        int mrow = n0 + l15;

        f32x4 C[4] = {{0,0,0,0}, {0,0,0,0}, {0,0,0,0}, {0,0,0,0}};
#pragma unroll
        for (int ks = 0; ks < 4; ++ks) {
            bf16x8 afr = sc8[(size_t)mrow * 16 + ks * 4 + quad];  // A[m][k=quad*8+j]
#pragma unroll
            for (int nt = 0; nt < 4; ++nt)
                C[nt] = __builtin_amdgcn_mfma_f32_16x16x32_bf16(afr, bfr[ks][nt], C[nt], 0, 0, 0);
        }

        int node = node_list ? node_list[n0 + l15] : (n0 + l15);

        float x[4][4];
        float ss[4] = {0.f, 0.f, 0.f, 0.f};
#pragma unroll
        for (int nt = 0; nt < 4; ++nt)
#pragma unroll
            for (int rg = 0; rg < 4; ++rg) {
                float v = C[nt][rg] + bias[nt];
                v = (v >= 0.f) ? v : 0.2f * v;
                x[nt][rg] = v;
                ss[rg] = fmaf(v, v, ss[rg]);
            }
#pragma unroll
        for (int rg = 0; rg < 4; ++rg) {
            ss[rg] += __shfl_xor(ss[rg], 1);
            ss[rg] += __shfl_xor(ss[rg], 2);
            ss[rg] += __shfl_xor(ss[rg], 4);
            ss[rg] += __shfl_xor(ss[rg], 8);
        }
#pragma unroll
        for (int rg = 0; rg < 4; ++rg) {
            float invr = 1.0f / fmaxf(sqrtf(ss[rg]), 1e-12f);
            if (out_mode) {
                int row = n0 + quad * 4 + rg;          // sampled: slot-direct
#pragma unroll
                for (int nt = 0; nt < 4; ++nt)
                    out[(size_t)row * 256 + col0 + nt * 16 + l15] = x[nt][rg] * invr;
            } else {
                int wnode = __shfl(node, quad * 4 + rg);
#pragma unroll
                for (int nt = 0; nt < 4; ++nt)
                    ego_out[(size_t)wnode * 64 + nt * 16 + l15] = (ushort)bf16_rne(x[nt][rg]);
                if (l15 == 0) inv_norm[wnode] = invr;
            }
        }
    }
}

extern "C" void kernel_launch(void* const* d_in, const int* in_sizes, int n_in,
                              void* d_out, int out_size, void* d_ws, size_t ws_size,
                              hipStream_t stream) {
    const int* users = (const int*)d_in[0];
    const int* pos   = (const int*)d_in[1];
    const int* neg   = (const int*)d_in[2];
    const int* arow  = (const int*)d_in[3];
    const int* acol  = (const int*)d_in[4];
    const float* aval = (const float*)d_in[5];
    const float* ue   = (const float*)d_in[6];
    const float* ie   = (const float*)d_in[7];
    const float* Wgc  = (const float*)d_in[8];
    const float* bgc  = (const float*)d_in[9];
    const float* Wbi  = (const float*)d_in[10];
    const float* bbi  = (const float*)d_in[11];
    float* out = (float*)d_out;

    char* ws = (char*)d_ws;
    size_t o = 0;
    ushort* ego_a   = (ushort*)(ws + o); o += 19200000;
    ushort* ego_b   = (ushort*)(ws + o); o += 19200000;
    uint4*  side_cs = (uint4*) (ws + o); o += 38400000;
    int2*   ecv     = (int2*)  (ws + o); o += (size_t)NNZ * 8;   // 19.2 MB
    int2*   tmp_cv  = (int2*)  (ws + o); o += (size_t)NNZ * 8;   // 19.2 MB
    int*    cnt     = (int*)   (ws + o); o += NB * BS_GRID * 4;  // 256 KB
    int*    row_start = (int*) (ws + o); o += 600064;
    float*  inv_a     = (float*)(ws + o); o += 600064;
    float*  inv_b     = (float*)(ws + o); o += 600064;
    int*    perm      = (int*) (ws + o); o += 600064;
    int*    samp      = (int*) (ws + o); o += 49152;
    int*    dhist     = (int*) (ws + o); o += 256;
    int*    gcur      = (int*) (ws + o); o += 256;

    const int gatherBlocks = (NSAMP * EMB) / 256;                // 3072

    // ---- CSR build (+ fused init) ----
    hipMemsetAsync(dhist, 0, 256, stream);
    binit<<<BS_GRID + INIT_BLOCKS, 256, 0, stream>>>(
        arow, cnt, (const float4*)ue, (const float4*)ie, ue, ie,
        users, pos, neg, (uint2*)ego_a, out, samp);
    scan64k<<<1, 1024, 0, stream>>>(cnt);
    bin_scatter<<<BS_GRID, 256, 0, stream>>>(arow, acol, aval, cnt, tmp_cv);
    csr_from_bins<<<NB, 256, 0, stream>>>(cnt, tmp_cv, ecv, row_start, dhist);
    deg_scan<<<1, 64, 0, stream>>>(dhist, gcur);
    deg_scatter<<<(N_NODES + 255) / 256, 256, 0, stream>>>(row_start, gcur, perm);

    // ---- layer 1: ego_a -> ego_b ----
    spmm_gather2<<<(N_NODES / 16 + 3) / 4, 256, 0, stream>>>(
        row_start, ecv, (const uint4*)ego_a, side_cs, perm, N_NODES / 16);
    gemm_dense2<<<(N_NODES + 255) / 256, 256, 0, stream>>>(
        side_cs, Wgc, bgc, Wbi, bbi, ego_b, inv_b, out, perm, N_NODES, 0, 0, 0,
        nullptr, nullptr, nullptr, 0);

    // ---- layer 2: ego_b -> ego_a  (+ piggy gather of layer-1 slice, col 64) ----
    spmm_gather2<<<(N_NODES / 16 + 3) / 4, 256, 0, stream>>>(
        row_start, ecv, (const uint4*)ego_b, side_cs, perm, N_NODES / 16);
    gemm_dense2<<<(N_NODES + 255) / 256 + gatherBlocks, 256, 0, stream>>>(
        side_cs, Wgc, bgc, Wbi, bbi, ego_a, inv_a, out, perm, N_NODES, 1, 0, 0,
        ego_b, inv_b, samp, 64);

    // ---- layer 3: sampled rows -> out col 192 (+ piggy gather of layer-2 slice, col 128) ----
    spmm_gather2<<<(NSAMP / 16) / 4, 256, 0, stream>>>(
        row_start, ecv, (const uint4*)ego_a, side_cs, samp, NSAMP / 16);
    gemm_dense2<<<NSAMP / 256 + gatherBlocks, 256, 0, stream>>>(
        side_cs, Wgc, bgc, Wbi, bbi, nullptr, nullptr, out, nullptr, NSAMP, 2, 1, 192,
        ego_a, inv_a, samp, 128);
}

// Round 15
// 602.683 us; speedup vs baseline: 1.0021x; 1.0021x over previous
//
#include <hip/hip_runtime.h>

typedef short bf16x8 __attribute__((ext_vector_type(8)));
typedef float f32x4  __attribute__((ext_vector_type(4)));

#define N_USER 50000
#define N_ITEM 100000
#define N_NODES 150000
#define EMB 64
#define NNZ 2400000
#define BATCH 4096
#define NSAMP (3 * BATCH)     // 12288 sampled rows
#define NB 256                // row-range buckets
#define RPB 587               // rows per bucket (256*587 = 150272 >= 150001)
#define BS_GRID 256           // binning blocks
#define EPB (NNZ / BS_GRID)   // 9375 edges per block

// bf16 round-to-nearest-even; low 16 bits hold the bf16
__device__ __forceinline__ unsigned int bf16_rne(float x) {
    unsigned int u = __float_as_uint(x);
    return (u + 0x7fffu + ((u >> 16) & 1u)) >> 16;
}
__device__ __forceinline__ float bflo(unsigned int u) { return __uint_as_float(u << 16); }
__device__ __forceinline__ float bfhi(unsigned int u) { return __uint_as_float(u & 0xffff0000u); }

__device__ __forceinline__ void fma8(float v, const uint4& x, float* acc) {
    acc[0] = fmaf(v, bflo(x.x), acc[0]); acc[1] = fmaf(v, bfhi(x.x), acc[1]);
    acc[2] = fmaf(v, bflo(x.y), acc[2]); acc[3] = fmaf(v, bfhi(x.y), acc[3]);
    acc[4] = fmaf(v, bflo(x.z), acc[4]); acc[5] = fmaf(v, bfhi(x.z), acc[5]);
    acc[6] = fmaf(v, bflo(x.w), acc[6]); acc[7] = fmaf(v, bfhi(x.w), acc[7]);
}
__device__ __forceinline__ void mul8(const uint4& s, const float* a, float* o) {
    o[0] = bflo(s.x) * a[0]; o[1] = bfhi(s.x) * a[1];
    o[2] = bflo(s.y) * a[2]; o[3] = bfhi(s.y) * a[3];
    o[4] = bflo(s.z) * a[4]; o[5] = bfhi(s.z) * a[5];
    o[6] = bflo(s.w) * a[6]; o[7] = bfhi(s.w) * a[7];
}
__device__ __forceinline__ uint4 pack8(const float* f) {
    return make_uint4((bf16_rne(f[1]) << 16) | bf16_rne(f[0]),
                      (bf16_rne(f[3]) << 16) | bf16_rne(f[2]),
                      (bf16_rne(f[5]) << 16) | bf16_rne(f[4]),
                      (bf16_rne(f[7]) << 16) | bf16_rne(f[6]));
}

// ========= fused: bin_count (blocks 0..255) + ego cast / layer-0 slice / samp list =========
#define SEG_A (N_NODES * 16)          // 2,400,000 float4->uint2 ego init
#define SEG_B (NSAMP * EMB)           // 786,432 gather0
#define INIT_BLOCKS ((SEG_A + SEG_B + NSAMP) / 256)   // 12495
__global__ __launch_bounds__(256) void binit(const int* __restrict__ rows,
                                             int* __restrict__ cnt,
                                             const float4* __restrict__ ue4,
                                             const float4* __restrict__ ie4,
                                             const float* __restrict__ ue,
                                             const float* __restrict__ ie,
                                             const int* __restrict__ users,
                                             const int* __restrict__ pos,
                                             const int* __restrict__ neg,
                                             uint2* __restrict__ ego_bf,
                                             float* __restrict__ out,
                                             int* __restrict__ samp) {
    __shared__ int h[NB];
    const int t = threadIdx.x;
    if (blockIdx.x < BS_GRID) {                        // ---- bin_count part ----
        const int blk = blockIdx.x;
        h[t] = 0;
        __syncthreads();
        const int e0 = blk * EPB;
        for (int i = t; i < EPB; i += 256) atomicAdd(&h[rows[e0 + i] / RPB], 1);
        __syncthreads();
        cnt[t * BS_GRID + blk] = h[t];
        return;
    }
    int i = (blockIdx.x - BS_GRID) * 256 + t;
    if (i < SEG_A) {
        const int NU4 = N_USER * 16;
        float4 v = (i < NU4) ? ue4[i] : ie4[i - NU4];
        ego_bf[i] = make_uint2((bf16_rne(v.y) << 16) | bf16_rne(v.x),
                               (bf16_rne(v.w) << 16) | bf16_rne(v.z));
    } else if (i < SEG_A + SEG_B) {
        int tt = i - SEG_A;
        int r = tt >> 6, d = tt & 63;
        int seg = r >> 12, idx = r & (BATCH - 1);
        int node = (seg == 0) ? users[idx] : N_USER + ((seg == 1) ? pos[idx] : neg[idx]);
        float v = (node < N_USER) ? ue[(size_t)node * EMB + d]
                                  : ie[(size_t)(node - N_USER) * EMB + d];
        out[(size_t)r * 256 + d] = v;
    } else {
        int tt = i - SEG_A - SEG_B;   // < NSAMP
        int seg = tt >> 12, idx = tt & (BATCH - 1);
        samp[tt] = (seg == 0) ? users[idx] : N_USER + ((seg == 1) ? pos[idx] : neg[idx]);
    }
}

__global__ __launch_bounds__(1024) void scan64k(int* __restrict__ cnt) {
    __shared__ int s[1024];
    const int t = threadIdx.x;
    int loc[64], sum = 0;
#pragma unroll
    for (int i = 0; i < 64; ++i) { loc[i] = cnt[t * 64 + i]; sum += loc[i]; }
    s[t] = sum;
    for (int off = 1; off < 1024; off <<= 1) {
        __syncthreads();
        int add = (t >= off) ? s[t - off] : 0;
        __syncthreads();
        s[t] += add;
    }
    __syncthreads();
    int run = s[t] - sum;
#pragma unroll
    for (int i = 0; i < 64; ++i) { cnt[t * 64 + i] = run; run += loc[i]; }
}

__global__ __launch_bounds__(256) void bin_scatter(const int* __restrict__ rows,
                                                   const int* __restrict__ cols,
                                                   const float* __restrict__ vals,
                                                   const int* __restrict__ base,
                                                   int2* __restrict__ tmp_cv) {
    __shared__ int gbase[NB];
    __shared__ int cur[NB];
    const int t = threadIdx.x, blk = blockIdx.x;
    gbase[t] = base[t * BS_GRID + blk];
    cur[t] = 0;
    __syncthreads();
    const int e0 = blk * EPB;
    for (int i = t; i < EPB; i += 256) {
        int e = e0 + i;
        int r = rows[e];
        int b = r / RPB;
        int slot = atomicAdd(&cur[b], 1);
        unsigned vv = (__float_as_uint(vals[e]) & ~1023u) | (unsigned)(r - b * RPB);
        tmp_cv[gbase[b] + slot] = make_int2(cols[e], (int)vv);
    }
}

__global__ __launch_bounds__(256) void csr_from_bins(const int* __restrict__ base,
                                                     const int2* __restrict__ tmp_cv,
                                                     int2* __restrict__ ecv,
                                                     int* __restrict__ row_start,
                                                     int* __restrict__ dhist) {
    __shared__ int rcnt[RPB];
    __shared__ int excl[RPB + 1];
    __shared__ int sc[256];
    __shared__ int lhist[64];
    const int b = blockIdx.x;
    const int row0 = b * RPB;
    const int t = threadIdx.x;
    const int beg = base[b * BS_GRID];
    const int end = (b == NB - 1) ? NNZ : base[(b + 1) * BS_GRID];

    for (int i = t; i < RPB; i += 256) rcnt[i] = 0;
    if (t < 64) lhist[t] = 0;
    __syncthreads();
    for (int i = beg + t; i < end; i += 256) atomicAdd(&rcnt[tmp_cv[i].y & 1023], 1);
    __syncthreads();

    for (int i = t; i < RPB; i += 256)
        if (row0 + i < N_NODES) atomicAdd(&lhist[min(rcnt[i], 63)], 1);

    const int i0 = t * 3, i1 = i0 + 1, i2 = i0 + 2;
    int v0 = (i0 < RPB) ? rcnt[i0] : 0;
    int v1 = (i1 < RPB) ? rcnt[i1] : 0;
    int v2 = (i2 < RPB) ? rcnt[i2] : 0;
    int sum = v0 + v1 + v2;
    sc[t] = sum;
    for (int off = 1; off < 256; off <<= 1) {
        __syncthreads();
        int add = (t >= off) ? sc[t - off] : 0;
        __syncthreads();
        sc[t] += add;
    }
    __syncthreads();
    int ex = sc[t] - sum;
    if (i0 <= RPB) excl[i0] = ex;
    if (i1 <= RPB) excl[i1] = ex + v0;
    if (i2 <= RPB) excl[i2] = ex + v0 + v1;
    if (t < 64) atomicAdd(&dhist[t], lhist[t]);
    __syncthreads();

    int lim = N_NODES + 1 - row0;
    if (lim > RPB) lim = RPB;
    for (int i = t; i < lim; i += 256) row_start[row0 + i] = beg + excl[i];
    __syncthreads();
    for (int i = t; i < RPB; i += 256) rcnt[i] = excl[i];
    __syncthreads();
    for (int i = beg + t; i < end; i += 256) {
        int2 rec = tmp_cv[i];
        int r10 = rec.y & 1023;
        int dst = beg + atomicAdd(&rcnt[r10], 1);
        ecv[dst] = make_int2(rec.x, rec.y & ~1023);
    }
}

// ===== degree sort (descending = LPT): 64-bin bases, then rank-and-scatter =====
__global__ void deg_scan(const int* __restrict__ dhist, int* __restrict__ gcur) {
    __shared__ int h[64];
    int t = threadIdx.x;
    h[t] = dhist[t];
    __syncthreads();
    int b0 = 0;
    for (int b = 63; b > t; --b) b0 += h[b];
    gcur[t] = b0;
}

__global__ __launch_bounds__(256) void deg_scatter(const int* __restrict__ row_start,
                                                   int* __restrict__ gcur,
                                                   int* __restrict__ perm) {
    __shared__ int lcnt[64];
    __shared__ int goff[64];
    const int t = threadIdx.x;
    const int i = blockIdx.x * 256 + t;
    if (t < 64) lcnt[t] = 0;
    __syncthreads();
    int bin = 0, myrank = 0;
    const bool valid = i < N_NODES;
    if (valid) {
        bin = min(row_start[i + 1] - row_start[i], 63);
        myrank = atomicAdd(&lcnt[bin], 1);
    }
    __syncthreads();
    if (t < 64 && lcnt[t] > 0) goff[t] = atomicAdd(&gcur[t], lcnt[t]);
    __syncthreads();
    if (valid) perm[goff[bin] + myrank] = i;
}

// ======== kernel A: lean CSR gather in MFMA A-layout -> side_cs ========
// lane (m=lane&15, quad=lane>>4) owns dims {quad*8..+7, 32+quad*8..+7} of its row.
// Epilogue: stage 16 rows x 256 B in wave-local LDS (17-pad), then 4 x 1KB CONTIGUOUS
// global stores — fixes round-14's partial-line write blowup (233 MB -> 38.4 MB).
__global__ __launch_bounds__(256, 6) void spmm_gather2(const int* __restrict__ row_start,
                                                       const int2* __restrict__ ecv,
                                                       const uint4* __restrict__ ego_bf,
                                                       uint4* __restrict__ side_cs, // n_rows x 16 uint4
                                                       const int* __restrict__ node_list,
                                                       int n_tiles) {
    __shared__ uint4 stg[4][16 * 17];                  // 17408 B: per-wave 16 rows x 16 (+pad)
    const int t = threadIdx.x;
    const int wv = t >> 6, lane = t & 63;
    const int tile = blockIdx.x * 4 + wv;
    if (tile >= n_tiles) return;
    const int l15 = lane & 15, quad = lane >> 4;

    const int r = tile * 16 + l15;
    const int node = node_list[r];
    const int s0 = row_start[node];
    const int s1 = row_start[node + 1];

    float acc[16];
#pragma unroll
    for (int i = 0; i < 16; ++i) acc[i] = 0.f;

    int eCur = s0 + quad;
    int2 recCur = (eCur < s1) ? ecv[eCur] : make_int2(0, 0);
    for (int e0 = s0; e0 < s1; e0 += 4) {
        int en = e0 + 4 + quad;
        int2 recN = (en < s1) ? ecv[en] : make_int2(0, 0);
        int   c[4]; float v[4];
#pragma unroll
        for (int j = 0; j < 4; ++j) {
            c[j] = __shfl(recCur.x, l15 + j * 16);
            v[j] = __int_as_float(__shfl(recCur.y, l15 + j * 16));
        }
        uint4 x0[4], x1[4];
#pragma unroll
        for (int j = 0; j < 4; ++j) {
            x0[j] = ego_bf[(size_t)c[j] * 8 + quad];
            x1[j] = ego_bf[(size_t)c[j] * 8 + 4 + quad];
        }
#pragma unroll
        for (int j = 0; j < 4; ++j) {
            fma8(v[j], x0[j], acc);
            fma8(v[j], x1[j], acc + 8);
        }
        recCur = recN;
    }

    const uint4 sf0 = ego_bf[(size_t)node * 8 + quad];
    const uint4 sf1 = ego_bf[(size_t)node * 8 + 4 + quad];

    // stage to LDS in row layout (wave-synchronous: same wave writes & reads)
    uint4* my = &stg[wv][l15 * 17];
    my[quad]     = pack8(acc);                         // side K 0..31
    my[4 + quad] = pack8(acc + 8);                     // side K 32..63
    float cs[8];
    mul8(sf0, acc, cs);
    my[8 + quad] = pack8(cs);                          // cs K 64..95
    mul8(sf1, acc + 8, cs);
    my[12 + quad] = pack8(cs);                         // cs K 96..127

    // transpose read + 4 x 1KB contiguous global stores
    uint4* gbase = side_cs + (size_t)tile * 256;       // 16 rows x 16 uint4
#pragma unroll
    for (int k = 0; k < 4; ++k) {
        int rr = k * 4 + (lane >> 4);                  // row 0..15
        int j  = lane & 15;                            // chunk 0..15
        gbase[k * 64 + lane] = stg[wv][rr * 17 + j];
    }
}

// ======== kernel B: MFMA GEMM [rows x 128]_bf16 @ [128 x 64] + bias/leaky/norm ========
#define WROW 136
__global__ __launch_bounds__(256) void gemm_dense2(const uint4* __restrict__ side_cs,
                                                   const float* __restrict__ Wgc,
                                                   const float* __restrict__ bgc,
                                                   const float* __restrict__ Wbi,
                                                   const float* __restrict__ bbi,
                                                   ushort* __restrict__ ego_out,
                                                   float* __restrict__ inv_norm,
                                                   float* __restrict__ out,
                                                   const int* __restrict__ node_list,
                                                   int n_rows, int layer, int out_mode, int col0,
                                                   const ushort* __restrict__ g_ego,
                                                   const float* __restrict__ g_inv,
                                                   const int* __restrict__ g_samp,
                                                   int g_col0) {
    const int t = threadIdx.x;
    const int spmmBlocks = (n_rows + 255) >> 8;        // 16 tiles (256 rows) per block
    if ((int)blockIdx.x >= spmmBlocks) {
        int i = (blockIdx.x - spmmBlocks) * 256 + t;   // grid sized to exactly NSAMP*EMB
        int r = i >> 6, d = i & 63;
        int node = g_samp[r];
        float v = __uint_as_float(((unsigned int)g_ego[(size_t)node * 64 + d]) << 16) * g_inv[node];
        out[(size_t)r * 256 + g_col0 + d] = v;
        return;
    }

    __shared__ ushort wT[64 * WROW];                   // wT[n][k] = [Wgc|Wbi]^T, bf16
    const float* Wg = Wgc + layer * 4096;
    const float* Wb = Wbi + layer * 4096;
    for (int idx = t; idx < 8192; idx += 256) {
        int n = idx >> 7, k = idx & 127;
        float w = (k < 64) ? Wg[k * 64 + n] : Wb[(k - 64) * 64 + n];
        wT[n * WROW + k] = (ushort)bf16_rne(w);
    }
    __syncthreads();

    const int lane = t & 63;
    const int wv = t >> 6;
    const int l15 = lane & 15, quad = lane >> 4;

    const bf16x8* wt8 = (const bf16x8*)wT;             // row stride WROW/8 = 17
    bf16x8 bfr[4][4];
#pragma unroll
    for (int ks = 0; ks < 4; ++ks)
#pragma unroll
        for (int nt = 0; nt < 4; ++nt)
            bfr[ks][nt] = wt8[(nt * 16 + l15) * 17 + ks * 4 + quad];

    float bias[4];
#pragma unroll
    for (int nt = 0; nt < 4; ++nt) {
        int ccol = nt * 16 + l15;
        bias[nt] = bgc[layer * 64 + ccol] + bbi[layer * 64 + ccol];
    }

    const bf16x8* sc8 = (const bf16x8*)side_cs;        // row stride 16

    for (int i = 0; i < 4; ++i) {
        int tile = (blockIdx.x * 4 + wv) * 4 + i;
        int n0 = tile * 16;
        if (n0 >= n_rows) break;
        int mrow = n0 + l15;

        f32x4 C[4] = {{0,0,0,0}, {0,0,0,0}, {0,0,0,0}, {0,0,0,0}};
#pragma unroll
        for (int ks = 0; ks < 4; ++ks) {
            bf16x8 afr = sc8[(size_t)mrow * 16 + ks * 4 + quad];  // A[m][k=quad*8+j]
#pragma unroll
            for (int nt = 0; nt < 4; ++nt)
                C[nt] = __builtin_amdgcn_mfma_f32_16x16x32_bf16(afr, bfr[ks][nt], C[nt], 0, 0, 0);
        }

        int node = node_list ? node_list[n0 + l15] : (n0 + l15);

        float x[4][4];
        float ss[4] = {0.f, 0.f, 0.f, 0.f};
#pragma unroll
        for (int nt = 0; nt < 4; ++nt)
#pragma unroll
            for (int rg = 0; rg < 4; ++rg) {
                float v = C[nt][rg] + bias[nt];
                v = (v >= 0.f) ? v : 0.2f * v;
                x[nt][rg] = v;
                ss[rg] = fmaf(v, v, ss[rg]);
            }
#pragma unroll
        for (int rg = 0; rg < 4; ++rg) {
            ss[rg] += __shfl_xor(ss[rg], 1);
            ss[rg] += __shfl_xor(ss[rg], 2);
            ss[rg] += __shfl_xor(ss[rg], 4);
            ss[rg] += __shfl_xor(ss[rg], 8);
        }
#pragma unroll
        for (int rg = 0; rg < 4; ++rg) {
            float invr = 1.0f / fmaxf(sqrtf(ss[rg]), 1e-12f);
            if (out_mode) {
                int row = n0 + quad * 4 + rg;          // sampled: slot-direct
#pragma unroll
                for (int nt = 0; nt < 4; ++nt)
                    out[(size_t)row * 256 + col0 + nt * 16 + l15] = x[nt][rg] * invr;
            } else {
                int wnode = __shfl(node, quad * 4 + rg);
#pragma unroll
                for (int nt = 0; nt < 4; ++nt)
                    ego_out[(size_t)wnode * 64 + nt * 16 + l15] = (ushort)bf16_rne(x[nt][rg]);
                if (l15 == 0) inv_norm[wnode] = invr;
            }
        }
    }
}

extern "C" void kernel_launch(void* const* d_in, const int* in_sizes, int n_in,
                              void* d_out, int out_size, void* d_ws, size_t ws_size,
                              hipStream_t stream) {
    const int* users = (const int*)d_in[0];
    const int* pos   = (const int*)d_in[1];
    const int* neg   = (const int*)d_in[2];
    const int* arow  = (const int*)d_in[3];
    const int* acol  = (const int*)d_in[4];
    const float* aval = (const float*)d_in[5];
    const float* ue   = (const float*)d_in[6];
    const float* ie   = (const float*)d_in[7];
    const float* Wgc  = (const float*)d_in[8];
    const float* bgc  = (const float*)d_in[9];
    const float* Wbi  = (const float*)d_in[10];
    const float* bbi  = (const float*)d_in[11];
    float* out = (float*)d_out;

    char* ws = (char*)d_ws;
    size_t o = 0;
    ushort* ego_a   = (ushort*)(ws + o); o += 19200000;
    ushort* ego_b   = (ushort*)(ws + o); o += 19200000;
    uint4*  side_cs = (uint4*) (ws + o); o += 38400000;
    int2*   ecv     = (int2*)  (ws + o); o += (size_t)NNZ * 8;   // 19.2 MB
    int2*   tmp_cv  = (int2*)  (ws + o); o += (size_t)NNZ * 8;   // 19.2 MB
    int*    cnt     = (int*)   (ws + o); o += NB * BS_GRID * 4;  // 256 KB
    int*    row_start = (int*) (ws + o); o += 600064;
    float*  inv_a     = (float*)(ws + o); o += 600064;
    float*  inv_b     = (float*)(ws + o); o += 600064;
    int*    perm      = (int*) (ws + o); o += 600064;
    int*    samp      = (int*) (ws + o); o += 49152;
    int*    dhist     = (int*) (ws + o); o += 256;
    int*    gcur      = (int*) (ws + o); o += 256;

    const int gatherBlocks = (NSAMP * EMB) / 256;                // 3072

    // ---- CSR build (+ fused init) ----
    hipMemsetAsync(dhist, 0, 256, stream);
    binit<<<BS_GRID + INIT_BLOCKS, 256, 0, stream>>>(
        arow, cnt, (const float4*)ue, (const float4*)ie, ue, ie,
        users, pos, neg, (uint2*)ego_a, out, samp);
    scan64k<<<1, 1024, 0, stream>>>(cnt);
    bin_scatter<<<BS_GRID, 256, 0, stream>>>(arow, acol, aval, cnt, tmp_cv);
    csr_from_bins<<<NB, 256, 0, stream>>>(cnt, tmp_cv, ecv, row_start, dhist);
    deg_scan<<<1, 64, 0, stream>>>(dhist, gcur);
    deg_scatter<<<(N_NODES + 255) / 256, 256, 0, stream>>>(row_start, gcur, perm);

    // ---- layer 1: ego_a -> ego_b ----
    spmm_gather2<<<(N_NODES / 16 + 3) / 4, 256, 0, stream>>>(
        row_start, ecv, (const uint4*)ego_a, side_cs, perm, N_NODES / 16);
    gemm_dense2<<<(N_NODES + 255) / 256, 256, 0, stream>>>(
        side_cs, Wgc, bgc, Wbi, bbi, ego_b, inv_b, out, perm, N_NODES, 0, 0, 0,
        nullptr, nullptr, nullptr, 0);

    // ---- layer 2: ego_b -> ego_a  (+ piggy gather of layer-1 slice, col 64) ----
    spmm_gather2<<<(N_NODES / 16 + 3) / 4, 256, 0, stream>>>(
        row_start, ecv, (const uint4*)ego_b, side_cs, perm, N_NODES / 16);
    gemm_dense2<<<(N_NODES + 255) / 256 + gatherBlocks, 256, 0, stream>>>(
        side_cs, Wgc, bgc, Wbi, bbi, ego_a, inv_a, out, perm, N_NODES, 1, 0, 0,
        ego_b, inv_b, samp, 64);

    // ---- layer 3: sampled rows -> out col 192 (+ piggy gather of layer-2 slice, col 128) ----
    spmm_gather2<<<(NSAMP / 16) / 4, 256, 0, stream>>>(
        row_start, ecv, (const uint4*)ego_a, side_cs, samp, NSAMP / 16);
    gemm_dense2<<<NSAMP / 256 + gatherBlocks, 256, 0, stream>>>(
        side_cs, Wgc, bgc, Wbi, bbi, nullptr, nullptr, out, nullptr, NSAMP, 2, 1, 192,
        ego_a, inv_a, samp, 128);
}

// Round 16
// 411.665 us; speedup vs baseline: 1.4671x; 1.4640x over previous
//
#include <hip/hip_runtime.h>

typedef short bf16x8 __attribute__((ext_vector_type(8)));
typedef float f32x4  __attribute__((ext_vector_type(4)));

#define N_USER 50000
#define N_ITEM 100000
#define N_NODES 150000
#define EMB 64
#define NNZ 2400000
#define BATCH 4096
#define NSAMP (3 * BATCH)     // 12288 sampled rows
#define NB 256                // row-range buckets
#define RPB 587               // rows per bucket (256*587 = 150272 >= 150001)
#define BS_GRID 256           // binning blocks
#define EPB (NNZ / BS_GRID)   // 9375 edges per block

// bf16 round-to-nearest-even; low 16 bits hold the bf16
__device__ __forceinline__ unsigned int bf16_rne(float x) {
    unsigned int u = __float_as_uint(x);
    return (u + 0x7fffu + ((u >> 16) & 1u)) >> 16;
}
__device__ __forceinline__ float bflo(unsigned int u) { return __uint_as_float(u << 16); }
__device__ __forceinline__ float bfhi(unsigned int u) { return __uint_as_float(u & 0xffff0000u); }

__device__ __forceinline__ void fma8(float v, const uint4& x, float* acc) {
    acc[0] = fmaf(v, bflo(x.x), acc[0]); acc[1] = fmaf(v, bfhi(x.x), acc[1]);
    acc[2] = fmaf(v, bflo(x.y), acc[2]); acc[3] = fmaf(v, bfhi(x.y), acc[3]);
    acc[4] = fmaf(v, bflo(x.z), acc[4]); acc[5] = fmaf(v, bfhi(x.z), acc[5]);
    acc[6] = fmaf(v, bflo(x.w), acc[6]); acc[7] = fmaf(v, bfhi(x.w), acc[7]);
}
__device__ __forceinline__ uint4 pack8(const float* f) {
    return make_uint4((bf16_rne(f[1]) << 16) | bf16_rne(f[0]),
                      (bf16_rne(f[3]) << 16) | bf16_rne(f[2]),
                      (bf16_rne(f[5]) << 16) | bf16_rne(f[4]),
                      (bf16_rne(f[7]) << 16) | bf16_rne(f[6]));
}

// ========= fused: bin_count (blocks 0..255) + ego cast / layer-0 slice / samp list =========
#define SEG_A (N_NODES * 16)          // 2,400,000 float4->uint2 ego init
#define SEG_B (NSAMP * EMB)           // 786,432 gather0
#define INIT_BLOCKS ((SEG_A + SEG_B + NSAMP) / 256)   // 12495
__global__ __launch_bounds__(256) void binit(const int* __restrict__ rows,
                                             int* __restrict__ cnt,
                                             const float4* __restrict__ ue4,
                                             const float4* __restrict__ ie4,
                                             const float* __restrict__ ue,
                                             const float* __restrict__ ie,
                                             const int* __restrict__ users,
                                             const int* __restrict__ pos,
                                             const int* __restrict__ neg,
                                             uint2* __restrict__ ego_bf,
                                             float* __restrict__ out,
                                             int* __restrict__ samp) {
    __shared__ int h[NB];
    const int t = threadIdx.x;
    if (blockIdx.x < BS_GRID) {                        // ---- bin_count part ----
        const int blk = blockIdx.x;
        h[t] = 0;
        __syncthreads();
        const int e0 = blk * EPB;
        for (int i = t; i < EPB; i += 256) atomicAdd(&h[rows[e0 + i] / RPB], 1);
        __syncthreads();
        cnt[t * BS_GRID + blk] = h[t];
        return;
    }
    int i = (blockIdx.x - BS_GRID) * 256 + t;
    if (i < SEG_A) {
        const int NU4 = N_USER * 16;
        float4 v = (i < NU4) ? ue4[i] : ie4[i - NU4];
        ego_bf[i] = make_uint2((bf16_rne(v.y) << 16) | bf16_rne(v.x),
                               (bf16_rne(v.w) << 16) | bf16_rne(v.z));
    } else if (i < SEG_A + SEG_B) {
        int tt = i - SEG_A;
        int r = tt >> 6, d = tt & 63;
        int seg = r >> 12, idx = r & (BATCH - 1);
        int node = (seg == 0) ? users[idx] : N_USER + ((seg == 1) ? pos[idx] : neg[idx]);
        float v = (node < N_USER) ? ue[(size_t)node * EMB + d]
                                  : ie[(size_t)(node - N_USER) * EMB + d];
        out[(size_t)r * 256 + d] = v;
    } else {
        int tt = i - SEG_A - SEG_B;   // < NSAMP
        int seg = tt >> 12, idx = tt & (BATCH - 1);
        samp[tt] = (seg == 0) ? users[idx] : N_USER + ((seg == 1) ? pos[idx] : neg[idx]);
    }
}

__global__ __launch_bounds__(1024) void scan64k(int* __restrict__ cnt) {
    __shared__ int s[1024];
    const int t = threadIdx.x;
    int loc[64], sum = 0;
#pragma unroll
    for (int i = 0; i < 64; ++i) { loc[i] = cnt[t * 64 + i]; sum += loc[i]; }
    s[t] = sum;
    for (int off = 1; off < 1024; off <<= 1) {
        __syncthreads();
        int add = (t >= off) ? s[t - off] : 0;
        __syncthreads();
        s[t] += add;
    }
    __syncthreads();
    int run = s[t] - sum;
#pragma unroll
    for (int i = 0; i < 64; ++i) { cnt[t * 64 + i] = run; run += loc[i]; }
}

__global__ __launch_bounds__(256) void bin_scatter(const int* __restrict__ rows,
                                                   const int* __restrict__ cols,
                                                   const float* __restrict__ vals,
                                                   const int* __restrict__ base,
                                                   int2* __restrict__ tmp_cv) {
    __shared__ int gbase[NB];
    __shared__ int cur[NB];
    const int t = threadIdx.x, blk = blockIdx.x;
    gbase[t] = base[t * BS_GRID + blk];
    cur[t] = 0;
    __syncthreads();
    const int e0 = blk * EPB;
    for (int i = t; i < EPB; i += 256) {
        int e = e0 + i;
        int r = rows[e];
        int b = r / RPB;
        int slot = atomicAdd(&cur[b], 1);
        unsigned vv = (__float_as_uint(vals[e]) & ~1023u) | (unsigned)(r - b * RPB);
        tmp_cv[gbase[b] + slot] = make_int2(cols[e], (int)vv);
    }
}

__global__ __launch_bounds__(256) void csr_from_bins(const int* __restrict__ base,
                                                     const int2* __restrict__ tmp_cv,
                                                     int2* __restrict__ ecv,
                                                     int* __restrict__ row_start) {
    __shared__ int rcnt[RPB];
    __shared__ int excl[RPB + 1];
    __shared__ int sc[256];
    const int b = blockIdx.x;
    const int row0 = b * RPB;
    const int t = threadIdx.x;
    const int beg = base[b * BS_GRID];
    const int end = (b == NB - 1) ? NNZ : base[(b + 1) * BS_GRID];

    for (int i = t; i < RPB; i += 256) rcnt[i] = 0;
    __syncthreads();
    for (int i = beg + t; i < end; i += 256) atomicAdd(&rcnt[tmp_cv[i].y & 1023], 1);
    __syncthreads();

    const int i0 = t * 3, i1 = i0 + 1, i2 = i0 + 2;
    int v0 = (i0 < RPB) ? rcnt[i0] : 0;
    int v1 = (i1 < RPB) ? rcnt[i1] : 0;
    int v2 = (i2 < RPB) ? rcnt[i2] : 0;
    int sum = v0 + v1 + v2;
    sc[t] = sum;
    for (int off = 1; off < 256; off <<= 1) {
        __syncthreads();
        int add = (t >= off) ? sc[t - off] : 0;
        __syncthreads();
        sc[t] += add;
    }
    __syncthreads();
    int ex = sc[t] - sum;
    if (i0 <= RPB) excl[i0] = ex;
    if (i1 <= RPB) excl[i1] = ex + v0;
    if (i2 <= RPB) excl[i2] = ex + v0 + v1;
    __syncthreads();

    int lim = N_NODES + 1 - row0;
    if (lim > RPB) lim = RPB;
    for (int i = t; i < lim; i += 256) row_start[row0 + i] = beg + excl[i];
    __syncthreads();
    for (int i = t; i < RPB; i += 256) rcnt[i] = excl[i];
    __syncthreads();
    for (int i = beg + t; i < end; i += 256) {
        int2 rec = tmp_cv[i];
        int r10 = rec.y & 1023;
        int dst = beg + atomicAdd(&rcnt[r10], 1);
        ecv[dst] = make_int2(rec.x, rec.y & ~1023);
    }
}

// ======== kernel A (round-9 shape, best measured: 68 µs, 73% occ, clean writes) ========
// wave per row; 8 edge-slots (j8) x 8 dim-groups (g8); 1 uint4 load per edge per lane.
__global__ __launch_bounds__(256) void spmm_gather(const int* __restrict__ row_start,
                                                   const int2* __restrict__ ecv,
                                                   const uint4* __restrict__ ego_bf, // 8 uint4/row
                                                   ushort* __restrict__ side_cs,    // n_rows x 128 bf16
                                                   const int* __restrict__ node_list,
                                                   int n_rows) {
    const int t = threadIdx.x;
    const int lane = t & 63;
    const int r = blockIdx.x * 4 + (t >> 6);
    if (r >= n_rows) return;
    const int node = node_list ? node_list[r] : r;
    const int j8 = lane >> 3;
    const int g8 = lane & 7;

    const int s0 = row_start[node];
    const int s1 = row_start[node + 1];
    const uint4 selfv = ego_bf[(size_t)node * 8 + g8];

    float acc[8] = {0.f, 0.f, 0.f, 0.f, 0.f, 0.f, 0.f, 0.f};
    for (int e0 = s0; e0 < s1; e0 += 64) {
        const int cnt = min(64, s1 - e0);
        int2 m = make_int2(0, 0);                      // zero-fill: pad slots are no-ops
        if (lane < cnt) m = ecv[e0 + lane];
        for (int jj = 0; jj < cnt; jj += 16) {         // 16 edges per iter (2 x 8-wide loads)
            int   i0 = jj + j8;
            int   c0 = __shfl(m.x, i0);
            float v0 = __int_as_float(__shfl(m.y, i0));
            const uint4 x0 = ego_bf[(size_t)c0 * 8 + g8];
            int   i1 = jj + 8 + j8;
            int   c1 = __shfl(m.x, i1);
            float v1 = __int_as_float(__shfl(m.y, i1));
            const uint4 x1 = ego_bf[(size_t)c1 * 8 + g8];
            fma8(v0, x0, acc);
            fma8(v1, x1, acc);
        }
    }
#pragma unroll
    for (int c = 0; c < 8; ++c) {
        acc[c] += __shfl_xor(acc[c], 8);
        acc[c] += __shfl_xor(acc[c], 16);
        acc[c] += __shfl_xor(acc[c], 32);
    }
    uint4* scs4 = (uint4*)side_cs;                     // row = 16 uint4 (256 B)
    if (j8 == 0) {
        scs4[(size_t)r * 16 + g8] = pack8(acc);        // side half (dims g8*8..+7)
    } else if (j8 == 1) {
        float cs[8] = { bflo(selfv.x) * acc[0], bfhi(selfv.x) * acc[1],
                        bflo(selfv.y) * acc[2], bfhi(selfv.y) * acc[3],
                        bflo(selfv.z) * acc[4], bfhi(selfv.z) * acc[5],
                        bflo(selfv.w) * acc[6], bfhi(selfv.w) * acc[7] };
        scs4[(size_t)r * 16 + 8 + g8] = pack8(cs);     // ego*side half
    }
}

// ======== kernel B: MFMA GEMM [rows x 128]_bf16 @ [128 x 64] + bias/leaky/norm ========
// mode 0: dense ego_out (bf16) + inv_norm; mode 1: slot-direct x*inv -> out at col0.
// Piggy-backs the previous layer's output-slice gather on extra trailing blocks.
#define WROW 136
__global__ __launch_bounds__(256) void gemm_dense2(const ushort* __restrict__ side_cs,
                                                   const float* __restrict__ Wgc,
                                                   const float* __restrict__ bgc,
                                                   const float* __restrict__ Wbi,
                                                   const float* __restrict__ bbi,
                                                   ushort* __restrict__ ego_out,
                                                   float* __restrict__ inv_norm,
                                                   float* __restrict__ out,
                                                   int n_rows, int layer, int out_mode, int col0,
                                                   const ushort* __restrict__ g_ego,
                                                   const float* __restrict__ g_inv,
                                                   const int* __restrict__ g_samp,
                                                   int g_col0) {
    const int t = threadIdx.x;
    const int spmmBlocks = (n_rows + 255) >> 8;        // 16 tiles (256 rows) per block
    if ((int)blockIdx.x >= spmmBlocks) {
        int i = (blockIdx.x - spmmBlocks) * 256 + t;   // grid sized to exactly NSAMP*EMB
        int r = i >> 6, d = i & 63;
        int node = g_samp[r];
        float v = __uint_as_float(((unsigned int)g_ego[(size_t)node * 64 + d]) << 16) * g_inv[node];
        out[(size_t)r * 256 + g_col0 + d] = v;
        return;
    }

    __shared__ ushort wT[64 * WROW];                   // wT[n][k] = [Wgc|Wbi]^T, bf16
    const float* Wg = Wgc + layer * 4096;
    const float* Wb = Wbi + layer * 4096;
    for (int idx = t; idx < 8192; idx += 256) {
        int n = idx >> 7, k = idx & 127;
        float w = (k < 64) ? Wg[k * 64 + n] : Wb[(k - 64) * 64 + n];
        wT[n * WROW + k] = (ushort)bf16_rne(w);
    }
    __syncthreads();

    const int lane = t & 63;
    const int wv = t >> 6;
    const int l15 = lane & 15, quad = lane >> 4;

    const bf16x8* wt8 = (const bf16x8*)wT;             // row stride WROW/8 = 17
    bf16x8 bfr[4][4];
#pragma unroll
    for (int ks = 0; ks < 4; ++ks)
#pragma unroll
        for (int nt = 0; nt < 4; ++nt)
            bfr[ks][nt] = wt8[(nt * 16 + l15) * 17 + ks * 4 + quad];

    float bias[4];
#pragma unroll
    for (int nt = 0; nt < 4; ++nt) {
        int ccol = nt * 16 + l15;
        bias[nt] = bgc[layer * 64 + ccol] + bbi[layer * 64 + ccol];
    }

    const bf16x8* sc8 = (const bf16x8*)side_cs;        // row stride 16

    for (int i = 0; i < 4; ++i) {
        int tile = (blockIdx.x * 4 + wv) * 4 + i;
        int n0 = tile * 16;
        if (n0 >= n_rows) break;
        int mrow = n0 + l15;

        f32x4 C[4] = {{0,0,0,0}, {0,0,0,0}, {0,0,0,0}, {0,0,0,0}};
#pragma unroll
        for (int ks = 0; ks < 4; ++ks) {
            bf16x8 afr = sc8[(size_t)mrow * 16 + ks * 4 + quad];  // A[m][k=(ks*4+quad)*8+j]
#pragma unroll
            for (int nt = 0; nt < 4; ++nt)
                C[nt] = __builtin_amdgcn_mfma_f32_16x16x32_bf16(afr, bfr[ks][nt], C[nt], 0, 0, 0);
        }

        float x[4][4];
        float ss[4] = {0.f, 0.f, 0.f, 0.f};
#pragma unroll
        for (int nt = 0; nt < 4; ++nt)
#pragma unroll
            for (int rg = 0; rg < 4; ++rg) {
                float v = C[nt][rg] + bias[nt];
                v = (v >= 0.f) ? v : 0.2f * v;
                x[nt][rg] = v;
                ss[rg] = fmaf(v, v, ss[rg]);
            }
#pragma unroll
        for (int rg = 0; rg < 4; ++rg) {
            ss[rg] += __shfl_xor(ss[rg], 1);
            ss[rg] += __shfl_xor(ss[rg], 2);
            ss[rg] += __shfl_xor(ss[rg], 4);
            ss[rg] += __shfl_xor(ss[rg], 8);
        }
#pragma unroll
        for (int rg = 0; rg < 4; ++rg) {
            int row = n0 + quad * 4 + rg;              // C/D: col=lane&15, row=quad*4+reg
            float invr = 1.0f / fmaxf(sqrtf(ss[rg]), 1e-12f);
            if (out_mode) {
#pragma unroll
                for (int nt = 0; nt < 4; ++nt)
                    out[(size_t)row * 256 + col0 + nt * 16 + l15] = x[nt][rg] * invr;
            } else {
#pragma unroll
                for (int nt = 0; nt < 4; ++nt)
                    ego_out[(size_t)row * 64 + nt * 16 + l15] = (ushort)bf16_rne(x[nt][rg]);
                if (l15 == 0) inv_norm[row] = invr;
            }
        }
    }
}

extern "C" void kernel_launch(void* const* d_in, const int* in_sizes, int n_in,
                              void* d_out, int out_size, void* d_ws, size_t ws_size,
                              hipStream_t stream) {
    const int* users = (const int*)d_in[0];
    const int* pos   = (const int*)d_in[1];
    const int* neg   = (const int*)d_in[2];
    const int* arow  = (const int*)d_in[3];
    const int* acol  = (const int*)d_in[4];
    const float* aval = (const float*)d_in[5];
    const float* ue   = (const float*)d_in[6];
    const float* ie   = (const float*)d_in[7];
    const float* Wgc  = (const float*)d_in[8];
    const float* bgc  = (const float*)d_in[9];
    const float* Wbi  = (const float*)d_in[10];
    const float* bbi  = (const float*)d_in[11];
    float* out = (float*)d_out;

    char* ws = (char*)d_ws;
    size_t o = 0;
    ushort* ego_a   = (ushort*)(ws + o); o += 19200000;
    ushort* ego_b   = (ushort*)(ws + o); o += 19200000;
    ushort* side_cs = (ushort*)(ws + o); o += 38400000;
    int2*   ecv     = (int2*)  (ws + o); o += (size_t)NNZ * 8;   // 19.2 MB
    int2*   tmp_cv  = (int2*)  (ws + o); o += (size_t)NNZ * 8;   // 19.2 MB
    int*    cnt     = (int*)   (ws + o); o += NB * BS_GRID * 4;  // 256 KB
    int*    row_start = (int*) (ws + o); o += 600064;
    float*  inv_a     = (float*)(ws + o); o += 600064;
    float*  inv_b     = (float*)(ws + o); o += 600064;
    int*    samp      = (int*) (ws + o); o += 49152;

    const int gatherBlocks = (NSAMP * EMB) / 256;                // 3072

    // ---- CSR build (+ fused init): 4 dispatches ----
    binit<<<BS_GRID + INIT_BLOCKS, 256, 0, stream>>>(
        arow, cnt, (const float4*)ue, (const float4*)ie, ue, ie,
        users, pos, neg, (uint2*)ego_a, out, samp);
    scan64k<<<1, 1024, 0, stream>>>(cnt);
    bin_scatter<<<BS_GRID, 256, 0, stream>>>(arow, acol, aval, cnt, tmp_cv);
    csr_from_bins<<<NB, 256, 0, stream>>>(cnt, tmp_cv, ecv, row_start);

    // ---- layer 1: ego_a -> ego_b ----
    spmm_gather<<<N_NODES / 4, 256, 0, stream>>>(
        row_start, ecv, (const uint4*)ego_a, side_cs, nullptr, N_NODES);
    gemm_dense2<<<(N_NODES + 255) / 256, 256, 0, stream>>>(
        side_cs, Wgc, bgc, Wbi, bbi, ego_b, inv_b, out, N_NODES, 0, 0, 0,
        nullptr, nullptr, nullptr, 0);

    // ---- layer 2: ego_b -> ego_a  (+ piggy gather of layer-1 slice, col 64) ----
    spmm_gather<<<N_NODES / 4, 256, 0, stream>>>(
        row_start, ecv, (const uint4*)ego_b, side_cs, nullptr, N_NODES);
    gemm_dense2<<<(N_NODES + 255) / 256 + gatherBlocks, 256, 0, stream>>>(
        side_cs, Wgc, bgc, Wbi, bbi, ego_a, inv_a, out, N_NODES, 1, 0, 0,
        ego_b, inv_b, samp, 64);

    // ---- layer 3: sampled rows -> out col 192 (+ piggy gather of layer-2 slice, col 128) ----
    spmm_gather<<<NSAMP / 4, 256, 0, stream>>>(
        row_start, ecv, (const uint4*)ego_a, side_cs, samp, NSAMP);
    gemm_dense2<<<NSAMP / 256 + gatherBlocks, 256, 0, stream>>>(
        side_cs, Wgc, bgc, Wbi, bbi, nullptr, nullptr, out, NSAMP, 2, 1, 192,
        ego_a, inv_a, samp, 128);
}